// Round 2
// baseline (2097.712 us; speedup 1.0000x reference)
//
#include <hip/hip_runtime.h>

#define N_NODES 500000
#define N_EDGES 8000000
#define IN_DIM 128
#define H1 32
#define H2 16

static __device__ __forceinline__ float bf2f(unsigned short u) {
    return __uint_as_float(((unsigned int)u) << 16);
}
static __device__ __forceinline__ unsigned short f2bf(float f) {
    unsigned int u = __float_as_uint(f);
    unsigned int r = (u + 0x7fffu + ((u >> 16) & 1u)) >> 16;
    return (unsigned short)r;
}
// load float element i from a buffer whose dtype is fp32 (isf32) or bf16
static __device__ __forceinline__ float ldf(const void* p, int i, bool isf32) {
    return isf32 ? ((const float*)p)[i] : bf2f(((const unsigned short*)p)[i]);
}

// ---- dtype sniffer: low 16 bits of fp32 mantissas decode to wild bf16s ----
// flag = 1 -> float inputs are fp32 ; flag = 0 -> bf16
__global__ __launch_bounds__(64) void k_sniff(const unsigned int* __restrict__ x,
                                              int* __restrict__ flag) {
    int bad = 0;
    for (int i = threadIdx.x; i < 1024; i += 64) {
        float v = __uint_as_float((x[i] & 0xffffu) << 16);
        if (!(fabsf(v) < 1e6f)) bad = 1;   // catches huge / inf / NaN
    }
    unsigned long long m = __ballot(bad);
    if (threadIdx.x == 0) *flag = (m != 0ull) ? 1 : 0;
}

// ---- degree: deg[d] += 1 for each edge (self-loop +1 added in k_dinv) ----
__global__ __launch_bounds__(256) void k_deg(const int* __restrict__ dst,
                                             float* __restrict__ deg) {
    int i = blockIdx.x * blockDim.x + threadIdx.x;
    int stride = gridDim.x * blockDim.x;
    for (int e = i; e < N_EDGES; e += stride) {
        unsigned d = (unsigned)dst[e];
        if (d < N_NODES) atomicAdd(&deg[d], 1.0f);
    }
}

__global__ __launch_bounds__(256) void k_dinv(float* __restrict__ deg) {
    int i = blockIdx.x * blockDim.x + threadIdx.x;
    if (i < N_NODES) deg[i] = rsqrtf(deg[i] + 1.0f);
}

// ---- y1 = (x @ W1) * dinv, thread per node, W1 staged fp32 in LDS ----
__global__ __launch_bounds__(256) void k_gemm1(const void* __restrict__ x,
                                               const void* __restrict__ w1,
                                               const float* __restrict__ dinv,
                                               float* __restrict__ y1,
                                               const int* __restrict__ flag) {
    __shared__ float wlds[IN_DIM * H1];
    const bool isf32 = (*flag != 0);
    for (int i = threadIdx.x; i < IN_DIM * H1; i += 256) wlds[i] = ldf(w1, i, isf32);
    __syncthreads();
    int node = blockIdx.x * 256 + threadIdx.x;
    if (node >= N_NODES) return;
    float acc[H1];
#pragma unroll
    for (int j = 0; j < H1; ++j) acc[j] = 0.f;

    if (isf32) {
        const float4* xr = reinterpret_cast<const float4*>((const float*)x + (size_t)node * IN_DIM);
#pragma unroll
        for (int kk = 0; kk < IN_DIM / 4; ++kk) {
            float4 v = xr[kk];
            float xe[4] = {v.x, v.y, v.z, v.w};
#pragma unroll
            for (int p = 0; p < 4; ++p) {
                const float* wr = &wlds[(kk * 4 + p) * H1];
#pragma unroll
                for (int j = 0; j < H1; ++j) acc[j] += xe[p] * wr[j];
            }
        }
    } else {
        const uint4* xr = reinterpret_cast<const uint4*>((const unsigned short*)x + (size_t)node * IN_DIM);
#pragma unroll
        for (int kk = 0; kk < IN_DIM / 8; ++kk) {
            uint4 xv = xr[kk];
            unsigned int uu[4] = {xv.x, xv.y, xv.z, xv.w};
#pragma unroll
            for (int p = 0; p < 4; ++p) {
                float xlo = __uint_as_float(uu[p] << 16);
                float xhi = __uint_as_float(uu[p] & 0xffff0000u);
                const float* w0 = &wlds[(kk * 8 + p * 2) * H1];
                const float* w1r = w0 + H1;
#pragma unroll
                for (int j = 0; j < H1; ++j) acc[j] += xlo * w0[j];
#pragma unroll
                for (int j = 0; j < H1; ++j) acc[j] += xhi * w1r[j];
            }
        }
    }
    float s = dinv[node];
    float4* out = reinterpret_cast<float4*>(y1 + (size_t)node * H1);
#pragma unroll
    for (int q = 0; q < H1 / 4; ++q)
        out[q] = make_float4(acc[4*q]*s, acc[4*q+1]*s, acc[4*q+2]*s, acc[4*q+3]*s);
}

// ---- scatter: agg[dst] += y[src], 32 (or 16) lanes per edge ----
__global__ __launch_bounds__(256) void k_scatter1(const int* __restrict__ src,
                                                  const int* __restrict__ dst,
                                                  const float* __restrict__ y1,
                                                  float* __restrict__ agg1) {
    const long long total = (long long)N_EDGES * H1;
    long long stride = (long long)gridDim.x * blockDim.x;
    for (long long t = (long long)blockIdx.x * blockDim.x + threadIdx.x; t < total; t += stride) {
        int e = (int)(t >> 5);
        int d = (int)(t & 31);
        unsigned s = (unsigned)src[e];
        unsigned dd = (unsigned)dst[e];
        if (s < N_NODES && dd < N_NODES) {
            float v = y1[(size_t)s * H1 + d];
            atomicAdd(&agg1[(size_t)dd * H1 + d], v);
        }
    }
}

__global__ __launch_bounds__(256) void k_scatter2(const int* __restrict__ src,
                                                  const int* __restrict__ dst,
                                                  const float* __restrict__ y2,
                                                  float* __restrict__ agg2) {
    const long long total = (long long)N_EDGES * H2;
    long long stride = (long long)gridDim.x * blockDim.x;
    for (long long t = (long long)blockIdx.x * blockDim.x + threadIdx.x; t < total; t += stride) {
        int e = (int)(t >> 4);
        int d = (int)(t & 15);
        unsigned s = (unsigned)src[e];
        unsigned dd = (unsigned)dst[e];
        if (s < N_NODES && dd < N_NODES) {
            float v = y2[(size_t)s * H2 + d];
            atomicAdd(&agg2[(size_t)dd * H2 + d], v);
        }
    }
}

// ---- h1 = relu(dinv*(agg1+y1)+b1); y2 = (h1 @ W2) * dinv  (h1 never stored) ----
__global__ __launch_bounds__(256) void k_fin1(const float* __restrict__ agg1,
                                              const float* __restrict__ y1,
                                              const float* __restrict__ dinv,
                                              const void* __restrict__ b1,
                                              const void* __restrict__ w2,
                                              float* __restrict__ y2,
                                              const int* __restrict__ flag) {
    __shared__ float w2l[H1 * H2];
    __shared__ float b1l[H1];
    const bool isf32 = (*flag != 0);
    for (int i = threadIdx.x; i < H1 * H2; i += 256) w2l[i] = ldf(w2, i, isf32);
    if (threadIdx.x < H1) b1l[threadIdx.x] = ldf(b1, threadIdx.x, isf32);
    __syncthreads();
    int node = blockIdx.x * 256 + threadIdx.x;
    if (node >= N_NODES) return;
    float s = dinv[node];
    const float* ar = agg1 + (size_t)node * H1;
    const float* yr = y1 + (size_t)node * H1;
    float h1v[H1];
#pragma unroll
    for (int k = 0; k < H1; ++k) {
        float v = s * (ar[k] + yr[k]) + b1l[k];
        h1v[k] = v > 0.f ? v : 0.f;
    }
    float acc[H2];
#pragma unroll
    for (int j = 0; j < H2; ++j) acc[j] = 0.f;
#pragma unroll
    for (int k = 0; k < H1; ++k) {
        float hk = h1v[k];
        const float* wr = &w2l[k * H2];
#pragma unroll
        for (int j = 0; j < H2; ++j) acc[j] += hk * wr[j];
    }
    float4* out = reinterpret_cast<float4*>(y2 + (size_t)node * H2);
#pragma unroll
    for (int q = 0; q < H2 / 4; ++q)
        out[q] = make_float4(acc[4*q]*s, acc[4*q+1]*s, acc[4*q+2]*s, acc[4*q+3]*s);
}

// ---- h2 = relu(dinv*(agg2+y2)+b2); logits = h2@Wfc+bfc; log_softmax ----
__global__ __launch_bounds__(256) void k_fin2(const float* __restrict__ agg2,
                                              const float* __restrict__ y2,
                                              const float* __restrict__ dinv,
                                              const void* __restrict__ b2,
                                              const void* __restrict__ wfc,
                                              const void* __restrict__ bfc,
                                              void* __restrict__ out,
                                              const int* __restrict__ flag) {
    __shared__ float wl[H2 * 2];
    __shared__ float b2l[H2];
    __shared__ float bfl[2];
    const bool isf32 = (*flag != 0);
    if (threadIdx.x < H2 * 2) wl[threadIdx.x] = ldf(wfc, threadIdx.x, isf32);
    if (threadIdx.x < H2) b2l[threadIdx.x] = ldf(b2, threadIdx.x, isf32);
    if (threadIdx.x < 2) bfl[threadIdx.x] = ldf(bfc, threadIdx.x, isf32);
    __syncthreads();
    int node = blockIdx.x * 256 + threadIdx.x;
    if (node >= N_NODES) return;
    float s = dinv[node];
    const float* ar = agg2 + (size_t)node * H2;
    const float* yr = y2 + (size_t)node * H2;
    float l0 = bfl[0], l1 = bfl[1];
#pragma unroll
    for (int k = 0; k < H2; ++k) {
        float v = s * (ar[k] + yr[k]) + b2l[k];
        v = v > 0.f ? v : 0.f;
        l0 += v * wl[k * 2];
        l1 += v * wl[k * 2 + 1];
    }
    float m = fmaxf(l0, l1);
    float lse = m + logf(__expf(l0 - m) + __expf(l1 - m));
    if (isf32) {
        reinterpret_cast<float2*>(out)[node] = make_float2(l0 - lse, l1 - lse);
    } else {
        unsigned int p = (unsigned int)f2bf(l0 - lse) | ((unsigned int)f2bf(l1 - lse) << 16);
        reinterpret_cast<unsigned int*>(out)[node] = p;
    }
}

extern "C" void kernel_launch(void* const* d_in, const int* in_sizes, int n_in,
                              void* d_out, int out_size, void* d_ws, size_t ws_size,
                              hipStream_t stream) {
    const void* x   = d_in[0];
    const int*  ei  = (const int*)d_in[1];
    const void* w1  = d_in[2];
    const void* b1  = d_in[3];
    const void* w2  = d_in[4];
    const void* b2  = d_in[5];
    const void* wfc = d_in[6];
    const void* bfc = d_in[7];
    const int* src = ei;
    const int* dst = ei + N_EDGES;

    // workspace layout (float units):
    // [0] flag | [64] dinv 500000 | [524352] y1 16M | [16524352] agg1 16M | [32524352] y2 8M
    // agg2 reuses y1's region (y1 dead after k_fin1). Total ~162.1 MB.
    float* ws   = (float*)d_ws;
    int*   flag = (int*)ws;
    float* dinv = ws + 64;
    float* y1   = ws + 524352;
    float* agg1 = ws + 16524352;
    float* y2   = ws + 32524352;
    float* agg2 = y1;

    const int nb_nodes = (N_NODES + 255) / 256;

    k_sniff<<<1, 64, 0, stream>>>((const unsigned int*)x, flag);
    hipMemsetAsync(dinv, 0, (size_t)N_NODES * sizeof(float), stream);
    k_deg<<<8192, 256, 0, stream>>>(dst, dinv);
    k_dinv<<<nb_nodes, 256, 0, stream>>>(dinv);
    k_gemm1<<<nb_nodes, 256, 0, stream>>>(x, w1, dinv, y1, flag);
    hipMemsetAsync(agg1, 0, (size_t)N_NODES * H1 * sizeof(float), stream);
    k_scatter1<<<16384, 256, 0, stream>>>(src, dst, y1, agg1);
    k_fin1<<<nb_nodes, 256, 0, stream>>>(agg1, y1, dinv, b1, w2, y2, flag);
    hipMemsetAsync(agg2, 0, (size_t)N_NODES * H2 * sizeof(float), stream);
    k_scatter2<<<16384, 256, 0, stream>>>(src, dst, y2, agg2);
    k_fin2<<<nb_nodes, 256, 0, stream>>>(agg2, y2, dinv, b2, wfc, bfc, d_out, flag);
}

// Round 3
// 1835.866 us; speedup vs baseline: 1.1426x; 1.1426x over previous
//
#include <hip/hip_runtime.h>

#define N_NODES 500000
#define N_EDGES 8000000
#define IN_DIM 128
#define H1 32
#define H2 16
#define NB_NODES 1954   // ceil(500000/256)

static __device__ __forceinline__ float bf2f(unsigned short u) {
    return __uint_as_float(((unsigned int)u) << 16);
}
static __device__ __forceinline__ unsigned short f2bf(float f) {
    unsigned int u = __float_as_uint(f);
    unsigned int r = (u + 0x7fffu + ((u >> 16) & 1u)) >> 16;
    return (unsigned short)r;
}
static __device__ __forceinline__ float ldf(const void* p, int i, bool isf32) {
    return isf32 ? ((const float*)p)[i] : bf2f(((const unsigned short*)p)[i]);
}

// ---- dtype sniffer: low 16 bits of fp32 mantissas decode to wild bf16s ----
__global__ __launch_bounds__(64) void k_sniff(const unsigned int* __restrict__ x,
                                              int* __restrict__ flag) {
    int bad = 0;
    for (int i = threadIdx.x; i < 1024; i += 64) {
        float v = __uint_as_float((x[i] & 0xffffu) << 16);
        if (!(fabsf(v) < 1e6f)) bad = 1;
    }
    unsigned long long m = __ballot(bad);
    if (threadIdx.x == 0) *flag = (m != 0ull) ? 1 : 0;
}

// ---- CSR build: histogram of dst ----
__global__ __launch_bounds__(256) void k_hist(const int* __restrict__ dst,
                                              int* __restrict__ cnt) {
    int i = blockIdx.x * blockDim.x + threadIdx.x;
    int stride = gridDim.x * blockDim.x;
    for (int e = i; e < N_EDGES; e += stride) {
        unsigned d = (unsigned)dst[e];
        if (d < N_NODES) atomicAdd(&cnt[d], 1);
    }
}

// ---- scan pass 1: per-256-block exclusive scan; block totals to partial ----
__global__ __launch_bounds__(256) void k_scan1(const int* __restrict__ cnt,
                                               int* __restrict__ off,
                                               int* __restrict__ partial) {
    __shared__ int tmp[256];
    int i = blockIdx.x * 256 + threadIdx.x;
    int v = (i < N_NODES) ? cnt[i] : 0;
    int val = v;
    tmp[threadIdx.x] = val;
    __syncthreads();
    for (int o = 1; o < 256; o <<= 1) {
        int t = (threadIdx.x >= (unsigned)o) ? tmp[threadIdx.x - o] : 0;
        __syncthreads();
        val += t;
        tmp[threadIdx.x] = val;
        __syncthreads();
    }
    if (i < N_NODES) off[i] = val - v;               // within-block exclusive
    if (threadIdx.x == 255) partial[blockIdx.x] = val; // block total
}

// ---- scan pass 2: single block scans the block totals (exclusive) ----
__global__ __launch_bounds__(256) void k_scan2(int* __restrict__ partial, int nb) {
    __shared__ int tmp[256];
    __shared__ int s_run;
    if (threadIdx.x == 0) s_run = 0;
    __syncthreads();
    for (int base = 0; base < nb; base += 256) {
        int i = base + threadIdx.x;
        int v = (i < nb) ? partial[i] : 0;
        int val = v;
        tmp[threadIdx.x] = val;
        __syncthreads();
        for (int o = 1; o < 256; o <<= 1) {
            int t = (threadIdx.x >= (unsigned)o) ? tmp[threadIdx.x - o] : 0;
            __syncthreads();
            val += t;
            tmp[threadIdx.x] = val;
            __syncthreads();
        }
        int run = s_run;
        if (i < nb) partial[i] = run + val - v;      // exclusive across all
        __syncthreads();
        if (threadIdx.x == 255) s_run = run + val;
        __syncthreads();
    }
}

// ---- scan pass 3: final offsets + cursor copy + dinv ----
__global__ __launch_bounds__(256) void k_scan3(const int* __restrict__ cnt,
                                               int* __restrict__ off,
                                               const int* __restrict__ partial,
                                               int* __restrict__ cur,
                                               float* __restrict__ dinv) {
    int i = blockIdx.x * 256 + threadIdx.x;
    if (i < N_NODES) {
        int v = off[i] + partial[blockIdx.x];
        off[i] = v;
        cur[i] = v;
        dinv[i] = rsqrtf((float)cnt[i] + 1.0f);
    }
    if (i == 0) off[N_NODES] = N_EDGES;
}

// ---- CSR fill: csr[slot] = src, slot = cur[dst]++ ----
__global__ __launch_bounds__(256) void k_fill(const int* __restrict__ src,
                                              const int* __restrict__ dst,
                                              int* __restrict__ cur,
                                              int* __restrict__ csr) {
    int i = blockIdx.x * blockDim.x + threadIdx.x;
    int stride = gridDim.x * blockDim.x;
    for (int e = i; e < N_EDGES; e += stride) {
        unsigned d = (unsigned)dst[e];
        unsigned s = (unsigned)src[e];
        if (d < N_NODES && s < N_NODES) {
            int slot = atomicAdd(&cur[d], 1);
            csr[slot] = (int)s;
        }
    }
}

// ---- y1 = (x @ W1) * dinv, thread per node, W1 staged fp32 in LDS ----
__global__ __launch_bounds__(256) void k_gemm1(const void* __restrict__ x,
                                               const void* __restrict__ w1,
                                               const float* __restrict__ dinv,
                                               float* __restrict__ y1,
                                               const int* __restrict__ flag) {
    __shared__ float wlds[IN_DIM * H1];
    const bool isf32 = (*flag != 0);
    for (int i = threadIdx.x; i < IN_DIM * H1; i += 256) wlds[i] = ldf(w1, i, isf32);
    __syncthreads();
    int node = blockIdx.x * 256 + threadIdx.x;
    if (node >= N_NODES) return;
    float acc[H1];
#pragma unroll
    for (int j = 0; j < H1; ++j) acc[j] = 0.f;

    if (isf32) {
        const float4* xr = reinterpret_cast<const float4*>((const float*)x + (size_t)node * IN_DIM);
#pragma unroll
        for (int kk = 0; kk < IN_DIM / 4; ++kk) {
            float4 v = xr[kk];
            float xe[4] = {v.x, v.y, v.z, v.w};
#pragma unroll
            for (int p = 0; p < 4; ++p) {
                const float* wr = &wlds[(kk * 4 + p) * H1];
#pragma unroll
                for (int j = 0; j < H1; ++j) acc[j] += xe[p] * wr[j];
            }
        }
    } else {
        const uint4* xr = reinterpret_cast<const uint4*>((const unsigned short*)x + (size_t)node * IN_DIM);
#pragma unroll
        for (int kk = 0; kk < IN_DIM / 8; ++kk) {
            uint4 xv = xr[kk];
            unsigned int uu[4] = {xv.x, xv.y, xv.z, xv.w};
#pragma unroll
            for (int p = 0; p < 4; ++p) {
                float xlo = __uint_as_float(uu[p] << 16);
                float xhi = __uint_as_float(uu[p] & 0xffff0000u);
                const float* w0 = &wlds[(kk * 8 + p * 2) * H1];
                const float* w1r = w0 + H1;
#pragma unroll
                for (int j = 0; j < H1; ++j) acc[j] += xlo * w0[j];
#pragma unroll
                for (int j = 0; j < H1; ++j) acc[j] += xhi * w1r[j];
            }
        }
    }
    float s = dinv[node];
    float4* out = reinterpret_cast<float4*>(y1 + (size_t)node * H1);
#pragma unroll
    for (int q = 0; q < H1 / 4; ++q)
        out[q] = make_float4(acc[4*q]*s, acc[4*q+1]*s, acc[4*q+2]*s, acc[4*q+3]*s);
}

// ---- pull layer 1 (+fused relu + GEMM H1->H2): 32 lanes per node ----
// agg = y1[node] + sum_{s in N(node)} y1[s]   (y1 pre-scaled by dinv)
// h1  = relu(dinv[node]*agg + b1); y2[node] = dinv[node]*(h1 @ W2)
__global__ __launch_bounds__(256) void k_pull1(const int* __restrict__ off,
                                               const int* __restrict__ csr,
                                               const float* __restrict__ y1,
                                               const float* __restrict__ dinv,
                                               const void* __restrict__ b1,
                                               const void* __restrict__ w2,
                                               float* __restrict__ y2,
                                               const int* __restrict__ flag) {
    __shared__ float w2l[H1 * H2];
    __shared__ float b1l[H1];
    __shared__ float hlds[256];
    const bool isf32 = (*flag != 0);
    for (int i = threadIdx.x; i < H1 * H2; i += 256) w2l[i] = ldf(w2, i, isf32);
    if (threadIdx.x < H1) b1l[threadIdx.x] = ldf(b1, threadIdx.x, isf32);
    __syncthreads();

    const int g = threadIdx.x >> 5;     // 8 node-groups of 32 lanes
    const int lane = threadIdx.x & 31;
    const int node = blockIdx.x * 8 + g;   // 62500*8 == 500000, exact

    float acc = y1[(size_t)node * H1 + lane];   // self-loop term
    const int beg = off[node], end = off[node + 1];
    for (int j = beg; j < end; j += 32) {
        int m = end - j; if (m > 32) m = 32;
        int sidx = (lane < m) ? csr[j + lane] : 0;
        for (int k = 0; k < m; ++k) {
            int s = __shfl(sidx, k, 32);
            acc += y1[(size_t)s * H1 + lane];
        }
    }
    float sc = dinv[node];
    float h = sc * acc + b1l[lane];
    h = h > 0.f ? h : 0.f;
    hlds[threadIdx.x] = h;              // same-wave write/read: no barrier needed
    if (lane < H2) {
        const float* hr = &hlds[g * 32];
        float a2 = 0.f;
#pragma unroll
        for (int k = 0; k < H1; ++k) a2 += hr[k] * w2l[k * H2 + lane];
        y2[(size_t)node * H2 + lane] = a2 * sc;
    }
}

// ---- pull layer 2 (+fused relu + FC + log_softmax): 16 lanes per node ----
__global__ __launch_bounds__(256) void k_pull2(const int* __restrict__ off,
                                               const int* __restrict__ csr,
                                               const float* __restrict__ y2,
                                               const float* __restrict__ dinv,
                                               const void* __restrict__ b2,
                                               const void* __restrict__ wfc,
                                               const void* __restrict__ bfc,
                                               void* __restrict__ out,
                                               const int* __restrict__ flag) {
    __shared__ float wl[H2 * 2];
    __shared__ float b2l[H2];
    __shared__ float bfl[2];
    const bool isf32 = (*flag != 0);
    if (threadIdx.x < H2 * 2) wl[threadIdx.x] = ldf(wfc, threadIdx.x, isf32);
    if (threadIdx.x < H2) b2l[threadIdx.x] = ldf(b2, threadIdx.x, isf32);
    if (threadIdx.x < 2) bfl[threadIdx.x] = ldf(bfc, threadIdx.x, isf32);
    __syncthreads();

    const int g = threadIdx.x >> 4;     // 16 node-groups of 16 lanes
    const int lane = threadIdx.x & 15;
    const int node = blockIdx.x * 16 + g;  // 31250*16 == 500000, exact

    float acc = y2[(size_t)node * H2 + lane];   // self-loop term
    const int beg = off[node], end = off[node + 1];
    for (int j = beg; j < end; j += 16) {
        int m = end - j; if (m > 16) m = 16;
        int sidx = (lane < m) ? csr[j + lane] : 0;
        for (int k = 0; k < m; ++k) {
            int s = __shfl(sidx, k, 16);
            acc += y2[(size_t)s * H2 + lane];
        }
    }
    float sc = dinv[node];
    float h = sc * acc + b2l[lane];
    h = h > 0.f ? h : 0.f;
    float t0 = h * wl[lane * 2];
    float t1 = h * wl[lane * 2 + 1];
#pragma unroll
    for (int o = 8; o >= 1; o >>= 1) {
        t0 += __shfl_xor(t0, o, 16);
        t1 += __shfl_xor(t1, o, 16);
    }
    if (lane == 0) {
        float l0 = t0 + bfl[0];
        float l1 = t1 + bfl[1];
        float mx = fmaxf(l0, l1);
        float lse = mx + logf(__expf(l0 - mx) + __expf(l1 - mx));
        if (isf32) {
            reinterpret_cast<float2*>(out)[node] = make_float2(l0 - lse, l1 - lse);
        } else {
            unsigned int p = (unsigned int)f2bf(l0 - lse) | ((unsigned int)f2bf(l1 - lse) << 16);
            reinterpret_cast<unsigned int*>(out)[node] = p;
        }
    }
}

extern "C" void kernel_launch(void* const* d_in, const int* in_sizes, int n_in,
                              void* d_out, int out_size, void* d_ws, size_t ws_size,
                              hipStream_t stream) {
    const void* x   = d_in[0];
    const int*  ei  = (const int*)d_in[1];
    const void* w1  = d_in[2];
    const void* b1  = d_in[3];
    const void* w2  = d_in[4];
    const void* b2  = d_in[5];
    const void* wfc = d_in[6];
    const void* bfc = d_in[7];
    const int* src = ei;
    const int* dst = ei + N_EDGES;

    // workspace layout (4-byte units), total ~136 MB:
    // flag@0 | dinv@64 | cnt@500096 | off@1000192(500001) | cur@1500224 |
    // partial@2000256(2048) | csr@2002304(8M) | y1@10002304(16M) | y2@26002304(8M)
    float* ws    = (float*)d_ws;
    int*   flag  = (int*)ws;
    float* dinv  = ws + 64;
    int*   cnt   = (int*)(ws + 500096);
    int*   off   = (int*)(ws + 1000192);
    int*   cur   = (int*)(ws + 1500224);
    int*   part  = (int*)(ws + 2000256);
    int*   csr   = (int*)(ws + 2002304);
    float* y1    = ws + 10002304;
    float* y2    = ws + 26002304;

    k_sniff<<<1, 64, 0, stream>>>((const unsigned int*)x, flag);
    hipMemsetAsync(cnt, 0, (size_t)N_NODES * sizeof(int), stream);
    k_hist<<<8192, 256, 0, stream>>>(dst, cnt);
    k_scan1<<<NB_NODES, 256, 0, stream>>>(cnt, off, part);
    k_scan2<<<1, 256, 0, stream>>>(part, NB_NODES);
    k_scan3<<<NB_NODES, 256, 0, stream>>>(cnt, off, part, cur, dinv);
    k_fill<<<8192, 256, 0, stream>>>(src, dst, cur, csr);
    k_gemm1<<<NB_NODES, 256, 0, stream>>>(x, w1, dinv, y1, flag);
    k_pull1<<<62500, 256, 0, stream>>>(off, csr, y1, dinv, b1, w2, y2, flag);
    k_pull2<<<31250, 256, 0, stream>>>(off, csr, y2, dinv, b2, wfc, bfc, d_out, flag);
}